// Round 3
// baseline (94.789 us; speedup 1.0000x reference)
//
#include <hip/hip_runtime.h>

// Problem constants: B=8, N=1024, C=768, H=12, D=64
// Algebraic collapse: v = spe_agg broadcast over sequence; softmax rows sum
// to 1, so attention output == v. Final:
//   out[b,n,:] = spe_agg[b,:] @ W_proj.T + b_proj   (independent of n and x)
#define BB 8
#define NN 1024
#define CC 768
#define COLS 64              // columns per block tile
#define RG 8                 // row groups per batch
#define ROWS (NN / RG)       // 128 rows per block

// One fused kernel: each block computes the 64 projection outputs it needs
// (wave-cooperative dots over C=768), then broadcasts them to its 128 rows.
// Grid: B * (C/COLS) * RG = 8 * 12 * 8 = 768 blocks of 256 threads.
__global__ __launch_bounds__(256) void fused_proj_bcast_kernel(
    const float* __restrict__ spe,   // (B, C)
    const float* __restrict__ Wp,    // (C, C) row-major: Wp[c*C + c']
    const float* __restrict__ bp,    // (C,)
    float* __restrict__ out)         // (B, N, C)
{
    __shared__ float rs[COLS];

    const int blk = blockIdx.x;
    const int rg  = blk & (RG - 1);        // row group 0..7
    const int t2  = blk >> 3;              // b*12 + ct
    const int ct  = t2 % (CC / COLS);      // col tile 0..11
    const int b   = t2 / (CC / COLS);      // batch 0..7

    const int tid  = threadIdx.x;
    const int wave = tid >> 6;
    const int lane = tid & 63;

    const float* srow = spe + (size_t)b * CC;

    // ---- phase 1: wave w computes cols ct*64 + w*16 + [0,16) ----
    for (int i = 0; i < 16; ++i) {
        const int col = ct * COLS + wave * 16 + i;
        const float* wrow = Wp + (size_t)col * CC;
        float acc = 0.0f;
#pragma unroll
        for (int j = 0; j < 3; ++j) {
            const int base = (j * 64 + lane) * 4;   // 16B/lane, coalesced
            float4 w4 = *reinterpret_cast<const float4*>(wrow + base);
            float4 s4 = *reinterpret_cast<const float4*>(srow + base);
            acc = fmaf(w4.x, s4.x, acc);
            acc = fmaf(w4.y, s4.y, acc);
            acc = fmaf(w4.z, s4.z, acc);
            acc = fmaf(w4.w, s4.w, acc);
        }
#pragma unroll
        for (int off = 32; off > 0; off >>= 1)
            acc += __shfl_down(acc, off, 64);
        if (lane == 0)
            rs[wave * 16 + i] = acc + bp[col];
    }
    __syncthreads();

    // ---- phase 2: broadcast to 128 rows x 64 cols, float4 stores ----
    const float4* rsv = reinterpret_cast<const float4*>(rs);
    const int c4 = tid & 15;    // float4 index within 64-col tile
    const int r0 = tid >> 4;    // 0..15: row within a 16-row sweep
    const float4 val = rsv[c4]; // LDS broadcast (2-way b128 aliasing = free)

    float4* outp = reinterpret_cast<float4*>(out) + (size_t)b * NN * (CC / 4);
    const int row_base = rg * ROWS;
#pragma unroll
    for (int it = 0; it < ROWS / 16; ++it) {
        const int row = row_base + it * 16 + r0;
        outp[(size_t)row * (CC / 4) + ct * 16 + c4] = val;
    }
}

extern "C" void kernel_launch(void* const* d_in, const int* in_sizes, int n_in,
                              void* d_out, int out_size, void* d_ws, size_t ws_size,
                              hipStream_t stream) {
    // inputs (fp32): 0=x (unused), 1=spe_agg (B,C), 2=W_qkv (unused),
    //                3=W_proj (C,C), 4=b_proj (C,)
    const float* spe = (const float*)d_in[1];
    const float* Wp  = (const float*)d_in[3];
    const float* bp  = (const float*)d_in[4];
    float* out = (float*)d_out;

    fused_proj_bcast_kernel<<<dim3(BB * (CC / COLS) * RG), dim3(256), 0, stream>>>(
        spe, Wp, bp, out);
}

// Round 5
// 86.383 us; speedup vs baseline: 1.0973x; 1.0973x over previous
//
#include <hip/hip_runtime.h>

// Problem constants: B=8, N=1024, C=768, H=12, D=64
// Algebraic collapse: v = spe_agg broadcast over sequence; softmax rows sum
// to 1, so attention output == v. Final:
//   out[b,n,:] = spe_agg[b,:] @ W_proj.T + b_proj   (independent of n and x)
#define BB 8
#define NN 1024
#define CC 768

// clang native vector type — required by __builtin_nontemporal_*
typedef float vf4 __attribute__((ext_vector_type(4)));

// Kernel A: r[b,c] = dot(spe[b,:], Wp[c,:]) + bp[c]   (fp32)
// One wave (64 lanes) per output element; 6144 outputs, 1536 blocks.
__global__ __launch_bounds__(256) void proj_gemv_kernel(
    const float* __restrict__ spe,   // (B, C)
    const float* __restrict__ Wp,    // (C, C) row-major: Wp[c*C + c']
    const float* __restrict__ bp,    // (C,)
    float* __restrict__ r)           // (B, C) out
{
    const int wave = (blockIdx.x * blockDim.x + threadIdx.x) >> 6;
    const int lane = threadIdx.x & 63;
    const int b = wave / CC;
    const int c = wave - b * CC;

    const vf4* wrow = reinterpret_cast<const vf4*>(Wp + (size_t)c * CC);
    const vf4* srow = reinterpret_cast<const vf4*>(spe + (size_t)b * CC);

    float acc = 0.0f;
#pragma unroll
    for (int j = 0; j < 3; ++j) {
        const int base = j * 64 + lane;          // vf4 index, coalesced 16B/lane
        vf4 w4 = __builtin_nontemporal_load(wrow + base);
        vf4 s4 = srow[base];
        acc = fmaf(w4.x, s4.x, acc);
        acc = fmaf(w4.y, s4.y, acc);
        acc = fmaf(w4.z, s4.z, acc);
        acc = fmaf(w4.w, s4.w, acc);
    }
    // wave-64 reduction
#pragma unroll
    for (int off = 32; off > 0; off >>= 1)
        acc += __shfl_down(acc, off, 64);

    if (lane == 0) {
        r[b * CC + c] = acc + bp[c];
    }
}

// Kernel B: out[b,n,:] = r[b,:] for all n. Non-temporal 16B stores.
// i indexes vf4 units; total B*N*C/4 = 1,572,864 units = 6144 blocks.
__global__ __launch_bounds__(256) void bcast_kernel(
    const vf4* __restrict__ r,   // (B, C/4)
    vf4* __restrict__ out)       // (B*N, C/4)
{
    const int i = blockIdx.x * blockDim.x + threadIdx.x;
    const int row = i / (CC / 4);          // b*N + n
    const int c4  = i - row * (CC / 4);
    const int b   = row >> 10;             // row / N, N=1024
    const vf4 v = r[b * (CC / 4) + c4];    // L1/L2-resident (24 KiB total)
    __builtin_nontemporal_store(v, out + i);
}

extern "C" void kernel_launch(void* const* d_in, const int* in_sizes, int n_in,
                              void* d_out, int out_size, void* d_ws, size_t ws_size,
                              hipStream_t stream) {
    // inputs (fp32): 0=x (unused), 1=spe_agg (B,C), 2=W_qkv (unused),
    //                3=W_proj (C,C), 4=b_proj (C,)
    const float* spe = (const float*)d_in[1];
    const float* Wp  = (const float*)d_in[3];
    const float* bp  = (const float*)d_in[4];
    float* r = (float*)d_ws;   // B*C fp32 = 24 KiB scratch

    // Kernel A: 6144 waves = 1536 blocks of 256 (4 waves/block)
    proj_gemv_kernel<<<dim3((BB * CC) / 4), dim3(256), 0, stream>>>(spe, Wp, bp, r);

    // Kernel B: 1,572,864 vf4 stores = 6144 blocks of 256
    bcast_kernel<<<dim3((BB * NN * CC / 4) / 256), dim3(256), 0, stream>>>(
        (const vf4*)r, (vf4*)d_out);
}